// Round 11
// baseline (136.346 us; speedup 1.0000x reference)
//
#include <hip/hip_runtime.h>
#include <hip/hip_cooperative_groups.h>
#include <math.h>

namespace cg = cooperative_groups;

#define BB 4
#define LL 256
#define TT 256
#define DD 512

// e^{2x} = exp2(x * 2/ln2)
#define EXP2K 2.885390081777927f

using short8 = __attribute__((ext_vector_type(8))) short;
using f32x4  = __attribute__((ext_vector_type(4))) float;

__device__ __forceinline__ unsigned cvt2bf(float a, float b) {
  unsigned r;
  asm("v_cvt_pk_bf16_f32 %0, %1, %2" : "=v"(r) : "v"(a), "v"(b));
  return r;  // lo = bf16(a), hi = bf16(b)
}

struct ProjSmem { char A[32 * 144]; char B[64 * 144]; };           // 13.8 KB
struct AttnSmem {
  float prt[2][4][64];          // (buf, dq, t-lane)
  float S[2][TT];               // raw scores per row
  float Pt[TT][2];              // probabilities, interleaved
  float rinv[2];
};                                                                  // 6.1 KB

// ---------------------------------------------------------------------------
// Phase body 1: combined projection GEMM via bf16 MFMA, fp32 accumulate.
// Rows 0..1023:   E1 = exp(2*(x@W1^T+b1))   row-major [B*L, D]
// Rows 1024..2047: E2c = exp(2*(mem@W2^T+b2)) CHUNKED [d>>2][b*T+t][d&3]
// ---------------------------------------------------------------------------
__device__ __forceinline__ void proj_body(
    ProjSmem& sm, int mtile, int ntile, int tid,
    const float* __restrict__ x, const float* __restrict__ mem,
    const float* __restrict__ W1, const float* __restrict__ b1,
    const float* __restrict__ W2, const float* __restrict__ b2,
    float* __restrict__ E1, float* __restrict__ E2c)
{
  const int m0 = mtile * 32;     // 0..2047 in steps of 32
  const int n0 = ntile * 64;     // 0..511  in steps of 64
  const bool second = (m0 >= BB * LL);

  const float* A    = second ? mem + (size_t)(m0 - BB * LL) * DD
                             : x   + (size_t)m0 * DD;
  const float* W    = second ? W2 : W1;
  const float* bias = second ? b2 : b1;

  const int srow = tid >> 4;
  const int kq   = (tid & 15) * 4;

  const int lane = tid & 63;
  const int wid  = tid >> 6;
  const int r0   = (wid & 1) * 16;
  const int n0w  = (wid >> 1) * 32;
  const int lr   = lane & 15;
  const int lg   = lane >> 4;

  const int aoff  = (r0 + lr) * 144 + lg * 16;
  const int boff0 = (n0w + lr) * 144 + lg * 16;
  const int boff1 = (n0w + 16 + lr) * 144 + lg * 16;

  f32x4 acc0 = {0.f, 0.f, 0.f, 0.f};
  f32x4 acc1 = {0.f, 0.f, 0.f, 0.f};

  for (int kc = 0; kc < DD; kc += 64) {
    __syncthreads();
#pragma unroll
    for (int p = 0; p < 2; ++p) {
      const int r = srow + p * 16;
      float4 v = *(const float4*)(A + (size_t)r * DD + kc + kq);
      uint2 u = {cvt2bf(v.x, v.y), cvt2bf(v.z, v.w)};
      *(uint2*)(sm.A + r * 144 + kq * 2) = u;
    }
#pragma unroll
    for (int p = 0; p < 4; ++p) {
      const int r = srow + p * 16;
      float4 v = *(const float4*)(W + (size_t)(n0 + r) * DD + kc + kq);
      uint2 u = {cvt2bf(v.x, v.y), cvt2bf(v.z, v.w)};
      *(uint2*)(sm.B + r * 144 + kq * 2) = u;
    }
    __syncthreads();
#pragma unroll
    for (int ks = 0; ks < 2; ++ks) {
      short8 af  = *(const short8*)(sm.A + aoff  + ks * 64);
      short8 bf0 = *(const short8*)(sm.B + boff0 + ks * 64);
      short8 bf1 = *(const short8*)(sm.B + boff1 + ks * 64);
      acc0 = __builtin_amdgcn_mfma_f32_16x16x32_bf16(af, bf0, acc0, 0, 0, 0);
      acc1 = __builtin_amdgcn_mfma_f32_16x16x32_bf16(af, bf1, acc1, 0, 0, 0);
    }
  }

#pragma unroll
  for (int nf = 0; nf < 2; ++nf) {
    const f32x4 a = nf ? acc1 : acc0;
    const int col = n0 + n0w + nf * 16 + lr;
    const float bv = bias[col];
#pragma unroll
    for (int i = 0; i < 4; ++i) {
      const int mrow = m0 + r0 + lg * 4 + i;
      const float val = exp2f((a[i] + bv) * EXP2K);
      if (!second) {
        E1[(size_t)mrow * DD + col] = val;
      } else {
        const int m2 = mrow - BB * LL;
        E2c[((size_t)(col >> 2) * (BB * TT) + m2) * 4 + (col & 3)] = val;
      }
    }
  }
}

// ---------------------------------------------------------------------------
// Phase body 2+3: FUSED score + softmax + PV (R8-proven).
// Block (b, lp) owns rows r0=lp, r1=255-lp: exactly 5 balanced 64-t-tiles.
// tanh(q+v) = 1 - 2/(Eq*Ev+1); S = -2*sum w/(Eq*Ev+1) (const drops in
// softmax). 4 waves x d-quarter, scalar q/w loads, LDS cross-dq reduce.
// ---------------------------------------------------------------------------
__device__ __forceinline__ void attn_body(
    AttnSmem& sm, int lp, int b, int tid,
    const float* __restrict__ E1, const float* __restrict__ E2c,
    const float* __restrict__ wt, const float* __restrict__ mem,
    const int* __restrict__ mask, float* __restrict__ out)
{
  const int tl = tid & 63;
  const int wv = tid >> 6;
  const int dq = __builtin_amdgcn_readfirstlane(wv);  // wave-uniform

  const int r0 = lp;
  const int r1 = 255 - lp;
  const int tc0 = r0 >> 6;
  const int tc1 = r1 >> 6;
  const int c0  = 4 - tc0;          // tiles for row0 (c0 + tiles_r1 == 5)

  const size_t strE2 = (size_t)(BB * TT);  // float4 stride per d4 plane
  const float4* wp = (const float4*)wt + dq * 32;

  // ---- score phase: 5 balanced tiles ----
  for (int it = 0; it < 5; ++it) {
    const int isr1 = (it >= c0);
    const int row  = isr1 ? r1 : r0;
    const int tc   = isr1 ? (tc1 + it - c0) : (tc0 + it);
    const int t    = tc * 64 + tl;

    const float4* qp = (const float4*)(E1 + (size_t)(b * LL + row) * DD) + dq * 32;
    const float4* vp = (const float4*)E2c + (size_t)(dq * 32) * strE2 + (b * TT + t);

    float a0 = 0.f, a1 = 0.f, a2 = 0.f, a3 = 0.f;
#pragma unroll 8
    for (int j = 0; j < 32; ++j) {
      float4 vv = vp[(size_t)j * strE2];
      float4 q  = qp[j];
      float4 w  = wp[j];
      a0 = fmaf(w.x, __builtin_amdgcn_rcpf(fmaf(q.x, vv.x, 1.0f)), a0);
      a1 = fmaf(w.y, __builtin_amdgcn_rcpf(fmaf(q.y, vv.y, 1.0f)), a1);
      a2 = fmaf(w.z, __builtin_amdgcn_rcpf(fmaf(q.z, vv.z, 1.0f)), a2);
      a3 = fmaf(w.w, __builtin_amdgcn_rcpf(fmaf(q.w, vv.w, 1.0f)), a3);
    }
    sm.prt[it & 1][dq][tl] = (a0 + a1) + (a2 + a3);
    __syncthreads();
    if (tid < 64) {
      const float* pp = &sm.prt[it & 1][0][0];
      sm.S[isr1][tc * 64 + tid] =
          (pp[tid] + pp[64 + tid]) + (pp[128 + tid] + pp[192 + tid]);
    }
  }
  __syncthreads();

  // ---- softmax: wave 0 -> r0, wave 1 -> r1 ----
  if (wv < 2) {
    const int row = wv ? r1 : r0;
    const int tb = tl * 4;
    float4 h = *(const float4*)(&sm.S[wv][tb]);
    const int4 mk = *(const int4*)(mask + b * TT + tb);
    float v0 = (tb + 0 >= row && mk.x != 0) ? -2.0f * h.x : -1e30f;
    float v1 = (tb + 1 >= row && mk.y != 0) ? -2.0f * h.y : -1e30f;
    float v2 = (tb + 2 >= row && mk.z != 0) ? -2.0f * h.z : -1e30f;
    float v3 = (tb + 3 >= row && mk.w != 0) ? -2.0f * h.w : -1e30f;
    float mx = fmaxf(fmaxf(v0, v1), fmaxf(v2, v3));
#pragma unroll
    for (int o = 1; o < 64; o <<= 1) mx = fmaxf(mx, __shfl_xor(mx, o));
    float e0 = __expf(v0 - mx), e1 = __expf(v1 - mx),
          e2 = __expf(v2 - mx), e3 = __expf(v3 - mx);
    sm.Pt[tb + 0][wv] = e0; sm.Pt[tb + 1][wv] = e1;
    sm.Pt[tb + 2][wv] = e2; sm.Pt[tb + 3][wv] = e3;
    float smm = (e0 + e1) + (e2 + e3);
#pragma unroll
    for (int o = 1; o < 64; o <<= 1) smm += __shfl_xor(smm, o);
    if (tl == 0) sm.rinv[wv] = 1.0f / smm;
  }
  __syncthreads();

  // ---- PV: 256 threads x 2 d-cols; loop split at r1 ----
  const int dd = tid * 2;
  const float* mp = mem + ((size_t)b * TT) * DD + dd;
  float ax0 = 0, ay0 = 0, ax1 = 0, ay1 = 0;
#pragma unroll 4
  for (int t = r0; t < r1; ++t) {          // row0 only
    const float p0 = sm.Pt[t][0];
    float2 mv = *(const float2*)(mp + (size_t)t * DD);
    ax0 = fmaf(p0, mv.x, ax0); ay0 = fmaf(p0, mv.y, ay0);
  }
#pragma unroll 4
  for (int t = r1; t < TT; ++t) {          // both rows
    float2 p  = *(const float2*)(&sm.Pt[t][0]);
    float2 mv = *(const float2*)(mp + (size_t)t * DD);
    ax0 = fmaf(p.x, mv.x, ax0); ay0 = fmaf(p.x, mv.y, ay0);
    ax1 = fmaf(p.y, mv.x, ax1); ay1 = fmaf(p.y, mv.y, ay1);
  }
  const float i0 = sm.rinv[0], i1 = sm.rinv[1];
  float2 o0 = {ax0 * i0, ay0 * i0};
  float2 o1 = {ax1 * i1, ay1 * i1};
  *(float2*)(out + ((size_t)(b * LL + r0)) * DD + dd) = o0;
  *(float2*)(out + ((size_t)(b * LL + r1)) * DD + dd) = o1;
}

// ---------------------------------------------------------------------------
// Standalone kernels (fallback path = proven R8 pair)
// ---------------------------------------------------------------------------
__global__ __launch_bounds__(256) void proj_gemm(
    const float* __restrict__ x, const float* __restrict__ mem,
    const float* __restrict__ W1, const float* __restrict__ b1,
    const float* __restrict__ W2, const float* __restrict__ b2,
    float* __restrict__ E1, float* __restrict__ E2c)
{
  __shared__ __align__(16) ProjSmem sm;
  proj_body(sm, blockIdx.x, blockIdx.y, threadIdx.x,
            x, mem, W1, b1, W2, b2, E1, E2c);
}

__global__ __launch_bounds__(256) void fused_attn(
    const float* __restrict__ E1, const float* __restrict__ E2c,
    const float* __restrict__ wt, const float* __restrict__ mem,
    const int* __restrict__ mask, float* __restrict__ out)
{
  __shared__ __align__(16) AttnSmem sm;
  attn_body(sm, blockIdx.x, blockIdx.y, threadIdx.x,
            E1, E2c, wt, mem, mask, out);
}

// ---------------------------------------------------------------------------
// ONE cooperative kernel: 512 blocks x 256 threads (exactly 2 blocks/CU,
// guaranteed co-resident under __launch_bounds__(256,2): VGPR<=256,
// LDS 13.8KB << 80KB). grid.sync between projection and attention.
// ---------------------------------------------------------------------------
__global__ __launch_bounds__(256, 2) void mega(
    const float* __restrict__ x, const float* __restrict__ mem,
    const float* __restrict__ W1, const float* __restrict__ b1,
    const float* __restrict__ W2, const float* __restrict__ b2,
    const float* __restrict__ wt, const int* __restrict__ mask,
    float* __restrict__ E1, float* __restrict__ E2c,
    float* __restrict__ out)
{
  __shared__ __align__(16) union { ProjSmem g; AttnSmem f; } sm;
  const int bid = blockIdx.x;

  proj_body(sm.g, bid >> 3, bid & 7, threadIdx.x,
            x, mem, W1, b1, W2, b2, E1, E2c);

  cg::this_grid().sync();

  attn_body(sm.f, bid & 127, bid >> 7, threadIdx.x,
            E1, E2c, wt, mem, mask, out);
}

extern "C" void kernel_launch(void* const* d_in, const int* in_sizes, int n_in,
                              void* d_out, int out_size, void* d_ws, size_t ws_size,
                              hipStream_t stream) {
  const float* x   = (const float*)d_in[0];
  const float* mem = (const float*)d_in[1];
  const float* W1  = (const float*)d_in[2];
  const float* b1  = (const float*)d_in[3];
  const float* W2  = (const float*)d_in[4];
  const float* b2  = (const float*)d_in[5];
  const float* wt  = (const float*)d_in[6];
  const int* mask  = (const int*)d_in[8];
  float* outp = (float*)d_out;

  float* E1  = (float*)d_ws;                     // [B*L, D]        2 MB
  float* E2c = E1 + (size_t)BB * LL * DD;        // [D/4][B*T][4]   2 MB (4 MB)

  void* args[] = {
      (void*)&x, (void*)&mem, (void*)&W1, (void*)&b1, (void*)&W2, (void*)&b2,
      (void*)&wt, (void*)&mask, (void*)&E1, (void*)&E2c, (void*)&outp};
  hipError_t err = hipLaunchCooperativeKernel(
      (const void*)mega, dim3(512), dim3(256), args, 0u, stream);
  if (err != hipSuccess) {
    // Fallback: proven R8 two-kernel pipeline (identical math).
    proj_gemm<<<dim3((BB * LL + BB * TT) / 32, DD / 64), 256, 0, stream>>>(
        x, mem, W1, b1, W2, b2, E1, E2c);
    fused_attn<<<dim3(LL / 2, BB), 256, 0, stream>>>(
        E1, E2c, wt, mem, mask, outp);
  }
}

// Round 12
// 57.137 us; speedup vs baseline: 2.3863x; 2.3863x over previous
//
#include <hip/hip_runtime.h>
#include <math.h>

#define BB 4
#define LL 256
#define TT 256
#define DD 512

// e^{2x} = exp2(x * 2/ln2)
#define EXP2K 2.885390081777927f

using short8 = __attribute__((ext_vector_type(8))) short;
using f32x4  = __attribute__((ext_vector_type(4))) float;
using ush4   = __attribute__((ext_vector_type(4))) unsigned short;

__device__ __forceinline__ unsigned cvt2bf(float a, float b) {
  unsigned r;
  asm("v_cvt_pk_bf16_f32 %0, %1, %2" : "=v"(r) : "v"(a), "v"(b));
  return r;  // lo = bf16(a), hi = bf16(b)
}
__device__ __forceinline__ float bf2f(unsigned short h) {
  union { unsigned u; float f; } c; c.u = ((unsigned)h) << 16; return c.f;
}
__device__ __forceinline__ unsigned short f2bf(float f) {  // RNE
  unsigned u = __float_as_uint(f);
  return (unsigned short)((u + 0x7fff + ((u >> 16) & 1)) >> 16);
}

// ---------------------------------------------------------------------------
// Kernel 1: combined projection GEMM via bf16 MFMA, fp32 accumulate.
// Rows 0..1023:    E1  = exp(2*(x@W1^T+b1))  f32 row-major [B*L, D]
// Rows 1024..2047: E2h = exp(2*(mem@W2^T+b2)) BF16 chunked [d>>2][b*T+t][d&3]
// Side-product (n0==0 second-half blocks): memh = bf16(mem) row-major.
// ---------------------------------------------------------------------------
__global__ __launch_bounds__(256) void proj_gemm(
    const float* __restrict__ x, const float* __restrict__ mem,
    const float* __restrict__ W1, const float* __restrict__ b1,
    const float* __restrict__ W2, const float* __restrict__ b2,
    float* __restrict__ E1, unsigned short* __restrict__ E2h,
    unsigned short* __restrict__ memh)
{
  __shared__ __align__(16) char Abuf[32 * 144];   // 32 rows x 64 bf16 (+pad)
  __shared__ __align__(16) char Bbuf[64 * 144];   // 64 cols x 64 bf16 (+pad)

  const int tid = threadIdx.x;
  const int m0 = blockIdx.x * 32;      // 0..2047 in steps of 32
  const int n0 = blockIdx.y * 64;      // 0..511  in steps of 64
  const bool second = (m0 >= BB * LL);

  const float* A    = second ? mem + (size_t)(m0 - BB * LL) * DD
                             : x   + (size_t)m0 * DD;
  const float* W    = second ? W2 : W1;
  const float* bias = second ? b2 : b1;

  const int srow = tid >> 4;           // 0..15 staging row
  const int kq   = (tid & 15) * 4;     // k quad within 64

  const int lane = tid & 63;
  const int wid  = tid >> 6;
  const int r0   = (wid & 1) * 16;
  const int n0w  = (wid >> 1) * 32;
  const int lr   = lane & 15;
  const int lg   = lane >> 4;

  const int aoff  = (r0 + lr) * 144 + lg * 16;
  const int boff0 = (n0w + lr) * 144 + lg * 16;
  const int boff1 = (n0w + 16 + lr) * 144 + lg * 16;

  f32x4 acc0 = {0.f, 0.f, 0.f, 0.f};
  f32x4 acc1 = {0.f, 0.f, 0.f, 0.f};

  for (int kc = 0; kc < DD; kc += 64) {
    __syncthreads();
#pragma unroll
    for (int p = 0; p < 2; ++p) {      // A: 32 rows
      const int r = srow + p * 16;
      float4 v = *(const float4*)(A + (size_t)r * DD + kc + kq);
      uint2 u = {cvt2bf(v.x, v.y), cvt2bf(v.z, v.w)};
      *(uint2*)(Abuf + r * 144 + kq * 2) = u;
      if (second && n0 == 0) {         // free bf16(mem) side-product
        *(uint2*)(memh + (size_t)(m0 - BB * LL + r) * DD + kc + kq) = u;
      }
    }
#pragma unroll
    for (int p = 0; p < 4; ++p) {      // B: 64 rows (= n cols)
      const int r = srow + p * 16;
      float4 v = *(const float4*)(W + (size_t)(n0 + r) * DD + kc + kq);
      uint2 u = {cvt2bf(v.x, v.y), cvt2bf(v.z, v.w)};
      *(uint2*)(Bbuf + r * 144 + kq * 2) = u;
    }
    __syncthreads();
#pragma unroll
    for (int ks = 0; ks < 2; ++ks) {
      short8 af  = *(const short8*)(Abuf + aoff  + ks * 64);
      short8 bf0 = *(const short8*)(Bbuf + boff0 + ks * 64);
      short8 bf1 = *(const short8*)(Bbuf + boff1 + ks * 64);
      acc0 = __builtin_amdgcn_mfma_f32_16x16x32_bf16(af, bf0, acc0, 0, 0, 0);
      acc1 = __builtin_amdgcn_mfma_f32_16x16x32_bf16(af, bf1, acc1, 0, 0, 0);
    }
  }

  // epilogue: C layout col=lane&15, row=(lane>>4)*4+i
#pragma unroll
  for (int nf = 0; nf < 2; ++nf) {
    const f32x4 a = nf ? acc1 : acc0;
    const int col = n0 + n0w + nf * 16 + lr;
    const float bv = bias[col];
#pragma unroll
    for (int i = 0; i < 4; ++i) {
      const int mrow = m0 + r0 + lg * 4 + i;
      const float val = exp2f((a[i] + bv) * EXP2K);
      if (!second) {
        E1[(size_t)mrow * DD + col] = val;
      } else {
        const int m2 = mrow - BB * LL;
        E2h[((size_t)(col >> 2) * (BB * TT) + m2) * 4 + (col & 3)] = f2bf(val);
      }
    }
  }
}

// ---------------------------------------------------------------------------
// Kernel 2: FUSED score + softmax + PV (R8 structure, bf16 streams).
// Block (b, lp) owns rows r0=lp, r1=255-lp: exactly 5 balanced 64-t-tiles.
// tanh(q+v) = 1 - 2/(Eq*Ev+1); S = -2*sum w/(Eq*Ev+1) (const drops in
// softmax). 4 waves x d-quarter (scalar q/w loads); vv loads are 8B bf16x4;
// PV reads bf16 memh (4B/thread/t). LDS cross-dq reduce.
// ---------------------------------------------------------------------------
__global__ __launch_bounds__(256) void fused_attn(
    const float* __restrict__ E1, const unsigned short* __restrict__ E2h,
    const float* __restrict__ wt, const unsigned short* __restrict__ memh,
    const int* __restrict__ mask, float* __restrict__ out)
{
  __shared__ float prt[2][4][64];          // (buf, dq, t-lane)
  __shared__ float S[2][TT];               // raw scores per row
  __shared__ __align__(8) float Pt[TT][2]; // probabilities, interleaved
  __shared__ float rinvS[2];

  const int tid = threadIdx.x;
  const int tl  = tid & 63;
  const int wv  = tid >> 6;
  const int dq  = __builtin_amdgcn_readfirstlane(wv);  // wave-uniform

  const int lp = blockIdx.x;        // 0..127
  const int b  = blockIdx.y;
  const int r0 = lp;
  const int r1 = 255 - lp;
  const int tc0 = r0 >> 6;
  const int tc1 = r1 >> 6;
  const int c0  = 4 - tc0;          // tiles for row0 (c0 + tiles_r1 == 5)

  const size_t strE2 = (size_t)(BB * TT);  // ush4 stride per d4 plane
  const float4* wp = (const float4*)wt + dq * 32;

  // ---- score phase: 5 balanced tiles ----
  for (int it = 0; it < 5; ++it) {
    const int isr1 = (it >= c0);
    const int row  = isr1 ? r1 : r0;
    const int tc   = isr1 ? (tc1 + it - c0) : (tc0 + it);
    const int t    = tc * 64 + tl;

    const float4* qp = (const float4*)(E1 + (size_t)(b * LL + row) * DD) + dq * 32;
    const ush4* vp = (const ush4*)E2h + (size_t)(dq * 32) * strE2 + (b * TT + t);

    float a0 = 0.f, a1 = 0.f, a2 = 0.f, a3 = 0.f;
#pragma unroll 8
    for (int j = 0; j < 32; ++j) {
      ush4 hv = vp[(size_t)j * strE2];
      float4 q = qp[j];
      float4 w = wp[j];
      a0 = fmaf(w.x, __builtin_amdgcn_rcpf(fmaf(q.x, bf2f(hv.x), 1.0f)), a0);
      a1 = fmaf(w.y, __builtin_amdgcn_rcpf(fmaf(q.y, bf2f(hv.y), 1.0f)), a1);
      a2 = fmaf(w.z, __builtin_amdgcn_rcpf(fmaf(q.z, bf2f(hv.z), 1.0f)), a2);
      a3 = fmaf(w.w, __builtin_amdgcn_rcpf(fmaf(q.w, bf2f(hv.w), 1.0f)), a3);
    }
    prt[it & 1][dq][tl] = (a0 + a1) + (a2 + a3);
    __syncthreads();
    if (tid < 64) {
      const float* pp = &prt[it & 1][0][0];
      S[isr1][tc * 64 + tid] =
          (pp[tid] + pp[64 + tid]) + (pp[128 + tid] + pp[192 + tid]);
    }
  }
  __syncthreads();

  // ---- softmax: wave 0 -> r0, wave 1 -> r1 ----
  if (wv < 2) {
    const int row = wv ? r1 : r0;
    const int tb = tl * 4;
    float4 h = *(const float4*)(&S[wv][tb]);
    const int4 mk = *(const int4*)(mask + b * TT + tb);
    float v0 = (tb + 0 >= row && mk.x != 0) ? -2.0f * h.x : -1e30f;
    float v1 = (tb + 1 >= row && mk.y != 0) ? -2.0f * h.y : -1e30f;
    float v2 = (tb + 2 >= row && mk.z != 0) ? -2.0f * h.z : -1e30f;
    float v3 = (tb + 3 >= row && mk.w != 0) ? -2.0f * h.w : -1e30f;
    float mx = fmaxf(fmaxf(v0, v1), fmaxf(v2, v3));
#pragma unroll
    for (int o = 1; o < 64; o <<= 1) mx = fmaxf(mx, __shfl_xor(mx, o));
    float e0 = __expf(v0 - mx), e1 = __expf(v1 - mx),
          e2 = __expf(v2 - mx), e3 = __expf(v3 - mx);
    Pt[tb + 0][wv] = e0; Pt[tb + 1][wv] = e1;
    Pt[tb + 2][wv] = e2; Pt[tb + 3][wv] = e3;
    float sm = (e0 + e1) + (e2 + e3);
#pragma unroll
    for (int o = 1; o < 64; o <<= 1) sm += __shfl_xor(sm, o);
    if (tl == 0) rinvS[wv] = 1.0f / sm;
  }
  __syncthreads();

  // ---- PV: 256 threads x 2 d-cols (bf16 memh); loop split at r1 ----
  const int dd = tid * 2;
  const unsigned short* mp = memh + ((size_t)b * TT) * DD + dd;
  float ax0 = 0, ay0 = 0, ax1 = 0, ay1 = 0;
#pragma unroll 4
  for (int t = r0; t < r1; ++t) {          // row0 only
    const float p0 = Pt[t][0];
    const unsigned u = *(const unsigned*)(mp + (size_t)t * DD);
    const float mx = __uint_as_float(u << 16);
    const float my = __uint_as_float(u & 0xffff0000u);
    ax0 = fmaf(p0, mx, ax0); ay0 = fmaf(p0, my, ay0);
  }
#pragma unroll 4
  for (int t = r1; t < TT; ++t) {          // both rows
    float2 p = *(const float2*)(&Pt[t][0]);
    const unsigned u = *(const unsigned*)(mp + (size_t)t * DD);
    const float mx = __uint_as_float(u << 16);
    const float my = __uint_as_float(u & 0xffff0000u);
    ax0 = fmaf(p.x, mx, ax0); ay0 = fmaf(p.x, my, ay0);
    ax1 = fmaf(p.y, mx, ax1); ay1 = fmaf(p.y, my, ay1);
  }
  const float i0 = rinvS[0], i1 = rinvS[1];
  float2 o0 = {ax0 * i0, ay0 * i0};
  float2 o1 = {ax1 * i1, ay1 * i1};
  *(float2*)(out + ((size_t)(b * LL + r0)) * DD + dd) = o0;
  *(float2*)(out + ((size_t)(b * LL + r1)) * DD + dd) = o1;
}

extern "C" void kernel_launch(void* const* d_in, const int* in_sizes, int n_in,
                              void* d_out, int out_size, void* d_ws, size_t ws_size,
                              hipStream_t stream) {
  const float* x   = (const float*)d_in[0];
  const float* mem = (const float*)d_in[1];
  const float* W1  = (const float*)d_in[2];
  const float* b1  = (const float*)d_in[3];
  const float* W2  = (const float*)d_in[4];
  const float* b2  = (const float*)d_in[5];
  const float* wt  = (const float*)d_in[6];
  const int* mask  = (const int*)d_in[8];
  float* outp = (float*)d_out;

  float* E1            = (float*)d_ws;                       // 2 MB f32
  unsigned short* E2h  = (unsigned short*)(E1 + (size_t)BB * LL * DD);   // 1 MB bf16
  unsigned short* memh = E2h + (size_t)BB * TT * DD;         // 1 MB bf16 (4 MB total)

  proj_gemm<<<dim3((BB * LL + BB * TT) / 32, DD / 64), 256, 0, stream>>>(
      x, mem, W1, b1, W2, b2, E1, E2h, memh);
  fused_attn<<<dim3(LL / 2, BB), 256, 0, stream>>>(
      E1, E2h, wt, memh, mask, outp);
}

// Round 13
// 42.528 us; speedup vs baseline: 3.2060x; 1.3435x over previous
//
#include <hip/hip_runtime.h>
#include <math.h>

#define BB 4
#define LL 256
#define TT 256
#define DD 512

// e^{2x} = exp2(x * 2/ln2)
#define EXP2K 2.885390081777927f

using short8 = __attribute__((ext_vector_type(8))) short;
using f32x4  = __attribute__((ext_vector_type(4))) float;

__device__ __forceinline__ unsigned cvt2bf(float a, float b) {
  unsigned r;
  asm("v_cvt_pk_bf16_f32 %0, %1, %2" : "=v"(r) : "v"(a), "v"(b));
  return r;  // lo = bf16(a), hi = bf16(b)
}

// ---------------------------------------------------------------------------
// Kernel 1: combined projection GEMM via bf16 MFMA, fp32 accumulate (R8-proven).
// Rows 0..1023:   E1  = exp(2*(x@W1^T+b1))   f32 row-major [B*L, D]
// Rows 1024..2047: E2c = exp(2*(mem@W2^T+b2)) f32 CHUNKED [d>>2][b*T+t][d&3]
// ---------------------------------------------------------------------------
__global__ __launch_bounds__(256) void proj_gemm(
    const float* __restrict__ x, const float* __restrict__ mem,
    const float* __restrict__ W1, const float* __restrict__ b1,
    const float* __restrict__ W2, const float* __restrict__ b2,
    float* __restrict__ E1, float* __restrict__ E2c)
{
  __shared__ __align__(16) char Abuf[32 * 144];   // 32 rows x 64 bf16 (+pad)
  __shared__ __align__(16) char Bbuf[64 * 144];   // 64 cols x 64 bf16 (+pad)

  const int tid = threadIdx.x;
  const int m0 = blockIdx.x * 32;      // 0..2047 in steps of 32
  const int n0 = blockIdx.y * 64;      // 0..511  in steps of 64
  const bool second = (m0 >= BB * LL);

  const float* A    = second ? mem + (size_t)(m0 - BB * LL) * DD
                             : x   + (size_t)m0 * DD;
  const float* W    = second ? W2 : W1;
  const float* bias = second ? b2 : b1;

  const int srow = tid >> 4;           // 0..15 staging row
  const int kq   = (tid & 15) * 4;     // k quad within 64

  const int lane = tid & 63;
  const int wid  = tid >> 6;
  const int r0   = (wid & 1) * 16;
  const int n0w  = (wid >> 1) * 32;
  const int lr   = lane & 15;
  const int lg   = lane >> 4;

  const int aoff  = (r0 + lr) * 144 + lg * 16;
  const int boff0 = (n0w + lr) * 144 + lg * 16;
  const int boff1 = (n0w + 16 + lr) * 144 + lg * 16;

  f32x4 acc0 = {0.f, 0.f, 0.f, 0.f};
  f32x4 acc1 = {0.f, 0.f, 0.f, 0.f};

  for (int kc = 0; kc < DD; kc += 64) {
    __syncthreads();
#pragma unroll
    for (int p = 0; p < 2; ++p) {      // A: 32 rows
      const int r = srow + p * 16;
      float4 v = *(const float4*)(A + (size_t)r * DD + kc + kq);
      uint2 u = {cvt2bf(v.x, v.y), cvt2bf(v.z, v.w)};
      *(uint2*)(Abuf + r * 144 + kq * 2) = u;
    }
#pragma unroll
    for (int p = 0; p < 4; ++p) {      // B: 64 rows (= n cols)
      const int r = srow + p * 16;
      float4 v = *(const float4*)(W + (size_t)(n0 + r) * DD + kc + kq);
      uint2 u = {cvt2bf(v.x, v.y), cvt2bf(v.z, v.w)};
      *(uint2*)(Bbuf + r * 144 + kq * 2) = u;
    }
    __syncthreads();
#pragma unroll
    for (int ks = 0; ks < 2; ++ks) {
      short8 af  = *(const short8*)(Abuf + aoff  + ks * 64);
      short8 bf0 = *(const short8*)(Bbuf + boff0 + ks * 64);
      short8 bf1 = *(const short8*)(Bbuf + boff1 + ks * 64);
      acc0 = __builtin_amdgcn_mfma_f32_16x16x32_bf16(af, bf0, acc0, 0, 0, 0);
      acc1 = __builtin_amdgcn_mfma_f32_16x16x32_bf16(af, bf1, acc1, 0, 0, 0);
    }
  }

  // epilogue: C layout col=lane&15, row=(lane>>4)*4+i
#pragma unroll
  for (int nf = 0; nf < 2; ++nf) {
    const f32x4 a = nf ? acc1 : acc0;
    const int col = n0 + n0w + nf * 16 + lr;
    const float bv = bias[col];
#pragma unroll
    for (int i = 0; i < 4; ++i) {
      const int mrow = m0 + r0 + lg * 4 + i;
      const float val = exp2f((a[i] + bv) * EXP2K);
      if (!second) {
        E1[(size_t)mrow * DD + col] = val;
      } else {
        const int m2 = mrow - BB * LL;
        E2c[((size_t)(col >> 2) * (BB * TT) + m2) * 4 + (col & 3)] = val;
      }
    }
  }
}

// ---------------------------------------------------------------------------
// Kernel 2: FUSED score + softmax + PV — R8 structure widened to 512 threads
// (8 waves = d-OCTANTS) for 4 waves/SIMD occupancy (R8's 4 waves = 2/SIMD
// was latency-bound: R11 mega counters showed total VALU issue ~12us vs 47us
// pipeline -> stalls dominate; R12 bf16 narrowing regressed -> not BW-bound).
// Block (b, lp) owns rows r0=lp, r1=255-lp: exactly 5 balanced 64-t-tiles.
// tanh(q+v) = 1 - 2/(Eq*Ev+1); S = -2*sum w/(Eq*Ev+1) (const drops in
// softmax). Per tile: 8 waves x 64-d-octant (scalar q/w loads, 16 coalesced
// float4 vector loads each), LDS cross-octant reduce (double-buffered).
// ---------------------------------------------------------------------------
__global__ __launch_bounds__(512) void fused_attn(
    const float* __restrict__ E1, const float* __restrict__ E2c,
    const float* __restrict__ wt, const float* __restrict__ mem,
    const int* __restrict__ mask, float* __restrict__ out)
{
  __shared__ float prt[2][8][64];          // (buf, d-octant, t-lane)
  __shared__ float S[2][TT];               // raw scores per row
  __shared__ __align__(8) float Pt[TT][2]; // probabilities, interleaved
  __shared__ float rinvS[2];

  const int tid = threadIdx.x;             // 0..511
  const int tl  = tid & 63;
  const int wv  = tid >> 6;                // 0..7
  const int dq  = __builtin_amdgcn_readfirstlane(wv);  // wave-uniform octant

  const int lp = blockIdx.x;        // 0..127
  const int b  = blockIdx.y;
  const int r0 = lp;
  const int r1 = 255 - lp;
  const int tc0 = r0 >> 6;
  const int tc1 = r1 >> 6;
  const int c0  = 4 - tc0;          // tiles for row0 (c0 + tiles_r1 == 5)

  const size_t strE2 = (size_t)(BB * TT);  // float4 stride per d4 plane
  const float4* wp = (const float4*)wt + dq * 16;

  // ---- score phase: 5 balanced tiles ----
  for (int it = 0; it < 5; ++it) {
    const int isr1 = (it >= c0);
    const int row  = isr1 ? r1 : r0;
    const int tc   = isr1 ? (tc1 + it - c0) : (tc0 + it);
    const int t    = tc * 64 + tl;

    const float4* qp = (const float4*)(E1 + (size_t)(b * LL + row) * DD) + dq * 16;
    const float4* vp = (const float4*)E2c + (size_t)(dq * 16) * strE2 + (b * TT + t);

    float a0 = 0.f, a1 = 0.f, a2 = 0.f, a3 = 0.f;
#pragma unroll 8
    for (int j = 0; j < 16; ++j) {
      float4 vv = vp[(size_t)j * strE2];
      float4 q  = qp[j];
      float4 w  = wp[j];
      a0 = fmaf(w.x, __builtin_amdgcn_rcpf(fmaf(q.x, vv.x, 1.0f)), a0);
      a1 = fmaf(w.y, __builtin_amdgcn_rcpf(fmaf(q.y, vv.y, 1.0f)), a1);
      a2 = fmaf(w.z, __builtin_amdgcn_rcpf(fmaf(q.z, vv.z, 1.0f)), a2);
      a3 = fmaf(w.w, __builtin_amdgcn_rcpf(fmaf(q.w, vv.w, 1.0f)), a3);
    }
    prt[it & 1][dq][tl] = (a0 + a1) + (a2 + a3);
    __syncthreads();
    if (tid < 64) {
      const float* pp = &prt[it & 1][0][0];
      S[isr1][tc * 64 + tid] =
          ((pp[tid] + pp[64 + tid]) + (pp[128 + tid] + pp[192 + tid])) +
          ((pp[256 + tid] + pp[320 + tid]) + (pp[384 + tid] + pp[448 + tid]));
    }
  }
  __syncthreads();

  // ---- softmax: wave 0 -> r0, wave 1 -> r1 ----
  if (wv < 2) {
    const int row = wv ? r1 : r0;
    const int tb = tl * 4;
    float4 h = *(const float4*)(&S[wv][tb]);
    const int4 mk = *(const int4*)(mask + b * TT + tb);
    float v0 = (tb + 0 >= row && mk.x != 0) ? -2.0f * h.x : -1e30f;
    float v1 = (tb + 1 >= row && mk.y != 0) ? -2.0f * h.y : -1e30f;
    float v2 = (tb + 2 >= row && mk.z != 0) ? -2.0f * h.z : -1e30f;
    float v3 = (tb + 3 >= row && mk.w != 0) ? -2.0f * h.w : -1e30f;
    float mx = fmaxf(fmaxf(v0, v1), fmaxf(v2, v3));
#pragma unroll
    for (int o = 1; o < 64; o <<= 1) mx = fmaxf(mx, __shfl_xor(mx, o));
    float e0 = __expf(v0 - mx), e1 = __expf(v1 - mx),
          e2 = __expf(v2 - mx), e3 = __expf(v3 - mx);
    Pt[tb + 0][wv] = e0; Pt[tb + 1][wv] = e1;
    Pt[tb + 2][wv] = e2; Pt[tb + 3][wv] = e3;
    float sm = (e0 + e1) + (e2 + e3);
#pragma unroll
    for (int o = 1; o < 64; o <<= 1) sm += __shfl_xor(sm, o);
    if (tl == 0) rinvS[wv] = 1.0f / sm;
  }
  __syncthreads();

  // ---- PV: 512 threads x 1 d-col; loop split at r1 ----
  const int dd = tid;
  const float* mp = mem + ((size_t)b * TT) * DD + dd;
  float ax0 = 0.f, ax1 = 0.f;
#pragma unroll 4
  for (int t = r0; t < r1; ++t) {          // row0 only
    const float p0 = Pt[t][0];
    ax0 = fmaf(p0, mp[(size_t)t * DD], ax0);
  }
#pragma unroll 4
  for (int t = r1; t < TT; ++t) {          // both rows
    float2 p = *(const float2*)(&Pt[t][0]);
    const float mv = mp[(size_t)t * DD];
    ax0 = fmaf(p.x, mv, ax0);
    ax1 = fmaf(p.y, mv, ax1);
  }
  out[((size_t)(b * LL + r0)) * DD + dd] = ax0 * rinvS[0];
  out[((size_t)(b * LL + r1)) * DD + dd] = ax1 * rinvS[1];
}

extern "C" void kernel_launch(void* const* d_in, const int* in_sizes, int n_in,
                              void* d_out, int out_size, void* d_ws, size_t ws_size,
                              hipStream_t stream) {
  const float* x   = (const float*)d_in[0];
  const float* mem = (const float*)d_in[1];
  const float* W1  = (const float*)d_in[2];
  const float* b1  = (const float*)d_in[3];
  const float* W2  = (const float*)d_in[4];
  const float* b2  = (const float*)d_in[5];
  const float* wt  = (const float*)d_in[6];
  const int* mask  = (const int*)d_in[8];
  float* outp = (float*)d_out;

  float* E1  = (float*)d_ws;                     // [B*L, D]        2 MB
  float* E2c = E1 + (size_t)BB * LL * DD;        // [D/4][B*T][4]   2 MB (4 MB)

  proj_gemm<<<dim3((BB * LL + BB * TT) / 32, DD / 64), 256, 0, stream>>>(
      x, mem, W1, b1, W2, b2, E1, E2c);
  fused_attn<<<dim3(LL / 2, BB), 512, 0, stream>>>(
      E1, E2c, wt, mem, mask, outp);
}